// Round 1
// baseline (1299.553 us; speedup 1.0000x reference)
//
#include <hip/hip_runtime.h>

constexpr int BB = 16;
constexpr int CI = 200;
constexpr int CO = 128;
constexpr int IMG_H = 128;
constexpr int IMG_W = 128;
constexpr int HW = IMG_H * IMG_W;    // 16384
constexpr int NN = 1024;
constexpr int KT = CO + CI;          // 328

// workspace layout (floats)
constexpr size_t OFF_X      = 0;                                  // 33,554,432
constexpr size_t OFF_HN     = (size_t)BB * CO * HW;               // + 2,097,152
constexpr size_t OFF_WLIN1T = OFF_HN + (size_t)BB * CO * NN;      // [200][128] bn1-folded W_lin^T
constexpr size_t OFF_WLIN2T = OFF_WLIN1T + (size_t)CI * CO;       // [200][128] bn2-folded
constexpr size_t OFF_BLIN1  = OFF_WLIN2T + (size_t)CI * CO;
constexpr size_t OFF_BLIN2  = OFF_BLIN1 + CO;
constexpr size_t OFF_WCXT   = OFF_BLIN2 + CO;                     // [328][128] final W for X path
constexpr size_t OFF_WCHT   = OFF_WCXT + (size_t)KT * CO;         // [328][128] final W for H path
constexpr size_t OFF_BFX    = OFF_WCHT + (size_t)KT * CO;
constexpr size_t OFF_BFH    = OFF_BFX + CO;
constexpr size_t OFF_XMSUM  = OFF_BFH + CO;                       // [16][128]
constexpr size_t OFF_GA     = OFF_XMSUM + (size_t)BB * CO;        // score*X_aggre
constexpr size_t OFF_GB     = OFF_GA + (size_t)BB * CO;           // 1-score

__device__ __forceinline__ float preluf(float v, float a) { return v >= 0.f ? v : a * v; }

#define GEMM_FMA_8x8(wrow, xrow)                                        \
  {                                                                     \
    float4 a0 = *(const float4*)(wrow);                                 \
    float4 a1 = *(const float4*)((wrow) + 4);                           \
    float4 b0 = *(const float4*)(xrow);                                 \
    float4 b1 = *(const float4*)((xrow) + 4);                           \
    float av[8] = {a0.x, a0.y, a0.z, a0.w, a1.x, a1.y, a1.z, a1.w};     \
    float bv[8] = {b0.x, b0.y, b0.z, b0.w, b1.x, b1.y, b1.z, b1.w};     \
    _Pragma("unroll")                                                   \
    for (int ii = 0; ii < 8; ++ii)                                      \
      _Pragma("unroll")                                                 \
      for (int jj = 0; jj < 8; ++jj)                                    \
        acc[ii][jj] = fmaf(av[ii], bv[jj], acc[ii][jj]);                \
  }

// ---------------------------------------------------------------------------
// Fold BN into weights, build transposed weight copies, zero mean accumulator.
// grid = 128 (one output row o), block = 256
__global__ __launch_bounds__(256) void k_prep(
    const float* __restrict__ bn1g, const float* __restrict__ bn1b,
    const float* __restrict__ bn1m, const float* __restrict__ bn1v,
    const float* __restrict__ bn2g, const float* __restrict__ bn2b,
    const float* __restrict__ bn2m, const float* __restrict__ bn2v,
    const float* __restrict__ Wlin, const float* __restrict__ blin,
    const float* __restrict__ Wfin, const float* __restrict__ bfin,
    float* ws)
{
  __shared__ float a1[CI], d1[CI], a2[CI], d2[CI];
  __shared__ float red[256];
  const int o = blockIdx.x;
  const int t = threadIdx.x;
  if (t < CI) {
    float s1 = bn1g[t] * rsqrtf(bn1v[t] + 1e-5f);
    a1[t] = s1; d1[t] = bn1b[t] - bn1m[t] * s1;
    float s2 = bn2g[t] * rsqrtf(bn2v[t] + 1e-5f);
    a2[t] = s2; d2[t] = bn2b[t] - bn2m[t] * s2;
  }
  __syncthreads();
  for (int k = t; k < CI; k += 256) {
    float w = Wlin[o * CI + k];
    ws[OFF_WLIN1T + (size_t)k * CO + o] = w * a1[k];
    ws[OFF_WLIN2T + (size_t)k * CO + o] = w * a2[k];
  }
  for (int k = t; k < KT; k += 256) {
    float w = Wfin[o * KT + k];
    float wx = w, wh = w;
    if (k >= CO) { wx = w * a1[k - CO]; wh = w * a2[k - CO]; }
    ws[OFF_WCXT + (size_t)k * CO + o] = wx;
    ws[OFF_WCHT + (size_t)k * CO + o] = wh;
  }
  if (t < BB) ws[OFF_XMSUM + (size_t)t * CO + o] = 0.f;

  float p1 = 0.f, p2 = 0.f, p3 = 0.f, p4 = 0.f;
  if (t < CI) {
    float wl = Wlin[o * CI + t];
    float wf = Wfin[o * KT + CO + t];
    p1 = wl * d1[t]; p2 = wl * d2[t];
    p3 = wf * d1[t]; p4 = wf * d2[t];
  }
  __syncthreads();
  red[t] = p1; __syncthreads();
  for (int s = 128; s > 0; s >>= 1) { if (t < s) red[t] += red[t + s]; __syncthreads(); }
  if (t == 0) ws[OFF_BLIN1 + o] = blin[o] + red[0];
  __syncthreads();
  red[t] = p2; __syncthreads();
  for (int s = 128; s > 0; s >>= 1) { if (t < s) red[t] += red[t + s]; __syncthreads(); }
  if (t == 0) ws[OFF_BLIN2 + o] = blin[o] + red[0];
  __syncthreads();
  red[t] = p3; __syncthreads();
  for (int s = 128; s > 0; s >>= 1) { if (t < s) red[t] += red[t + s]; __syncthreads(); }
  if (t == 0) ws[OFF_BFX + o] = bfin[o] + red[0];
  __syncthreads();
  red[t] = p4; __syncthreads();
  for (int s = 128; s > 0; s >>= 1) { if (t < s) red[t] += red[t + s]; __syncthreads(); }
  if (t == 0) ws[OFF_BFH + o] = bfin[o] + red[0];
}

// ---------------------------------------------------------------------------
// Hn = Wlin2 @ H_in + blin2   (16,128,1024).  grid (8,16), block 256.
__global__ __launch_bounds__(256) void k_hn(const float* __restrict__ Hin, float* ws)
{
  __shared__ __align__(16) float smem[2048];
  float* wt = smem;
  float* xb = smem + 1024;
  const float* WT = ws + OFF_WLIN2T;
  const float* bias = ws + OFF_BLIN2;
  float* Hn = ws + OFF_HN;
  const int bb = blockIdx.y;
  const int col0 = blockIdx.x * 128;
  const int tid = threadIdx.x;
  const int ty = tid >> 4, tx = tid & 15;
  const int kk = tid >> 5, j4 = tid & 31;
  float acc[8][8];
#pragma unroll
  for (int i = 0; i < 8; ++i)
#pragma unroll
    for (int j = 0; j < 8; ++j) acc[i][j] = 0.f;
  const float* Bsrc = Hin + (size_t)bb * CI * NN + col0;
  for (int k0 = 0; k0 < CI; k0 += 8) {
    ((float4*)wt)[tid] = ((const float4*)(WT + (size_t)(k0 + kk) * CO))[j4];
    ((float4*)xb)[tid] = ((const float4*)(Bsrc + (size_t)(k0 + kk) * NN))[j4];
    __syncthreads();
#pragma unroll
    for (int k = 0; k < 8; ++k) {
      const float* wrow = wt + k * 128 + ty * 8;
      const float* xrow = xb + k * 128 + tx * 8;
      GEMM_FMA_8x8(wrow, xrow);
    }
    __syncthreads();
  }
#pragma unroll
  for (int i = 0; i < 8; ++i) {
    const int o = ty * 8 + i;
    const float bi = bias[o];
    float* dst = Hn + ((size_t)(bb * CO + o)) * NN + col0 + tx * 8;
    *(float4*)dst       = make_float4(acc[i][0] + bi, acc[i][1] + bi, acc[i][2] + bi, acc[i][3] + bi);
    *(float4*)(dst + 4) = make_float4(acc[i][4] + bi, acc[i][5] + bi, acc[i][6] + bi, acc[i][7] + bi);
  }
}

// ---------------------------------------------------------------------------
// X = Wlin1 @ X_in + blin1 (16,128,16384) + fused per-(b,o) sum for X_mean.
// grid (128,16), block 256.
__global__ __launch_bounds__(256) void k_x(const float* __restrict__ Xin, float* ws)
{
  __shared__ __align__(16) float smem[2048];
  float* wt = smem;
  float* xb = smem + 1024;
  const float* WT = ws + OFF_WLIN1T;
  const float* bias = ws + OFF_BLIN1;
  float* X = ws + OFF_X;
  const int bb = blockIdx.y;
  const int col0 = blockIdx.x * 128;
  const int tid = threadIdx.x;
  const int ty = tid >> 4, tx = tid & 15;
  const int kk = tid >> 5, j4 = tid & 31;
  float acc[8][8];
#pragma unroll
  for (int i = 0; i < 8; ++i)
#pragma unroll
    for (int j = 0; j < 8; ++j) acc[i][j] = 0.f;
  const float* Bsrc = Xin + (size_t)bb * CI * HW + col0;
  for (int k0 = 0; k0 < CI; k0 += 8) {
    ((float4*)wt)[tid] = ((const float4*)(WT + (size_t)(k0 + kk) * CO))[j4];
    ((float4*)xb)[tid] = ((const float4*)(Bsrc + (size_t)(k0 + kk) * HW))[j4];
    __syncthreads();
#pragma unroll
    for (int k = 0; k < 8; ++k) {
      const float* wrow = wt + k * 128 + ty * 8;
      const float* xrow = xb + k * 128 + tx * 8;
      GEMM_FMA_8x8(wrow, xrow);
    }
    __syncthreads();
  }
  float ps[8];
#pragma unroll
  for (int i = 0; i < 8; ++i) {
    const int o = ty * 8 + i;
    const float bi = bias[o];
    float s = 0.f;
#pragma unroll
    for (int j = 0; j < 8; ++j) s += acc[i][j];
    ps[i] = s;  // pre-bias sum; bias added in k_small
    float* dst = X + ((size_t)(bb * CO + o)) * HW + col0 + tx * 8;
    *(float4*)dst       = make_float4(acc[i][0] + bi, acc[i][1] + bi, acc[i][2] + bi, acc[i][3] + bi);
    *(float4*)(dst + 4) = make_float4(acc[i][4] + bi, acc[i][5] + bi, acc[i][6] + bi, acc[i][7] + bi);
  }
  __syncthreads();
  float* red = smem;  // 2048 floats = [128][16]
#pragma unroll
  for (int i = 0; i < 8; ++i) red[(ty * 8 + i) * 16 + tx] = ps[i];
  __syncthreads();
  if (tid < 128) {
    float s = 0.f;
#pragma unroll
    for (int u = 0; u < 16; ++u) s += red[tid * 16 + u];
    atomicAdd(ws + OFF_XMSUM + (size_t)bb * CO + tid, s);
  }
}

// ---------------------------------------------------------------------------
// Per-batch: X_mean, q=X_sim, u=Wsim^T q, logits->sigmoid->softmax, X_aggre,
// score, gate coefficients. grid 16, block 256.
__global__ __launch_bounds__(256) void k_small(
    const float* __restrict__ Wsim, const float* __restrict__ bsim,
    const float* __restrict__ Wscore, const float* __restrict__ bscore,
    float* ws)
{
  __shared__ float xmean[128], q[128], u[128], xa[128];
  __shared__ float sim[1025];
  __shared__ float red[256];
  __shared__ float cq_sh, l0_sh, msh, ssh;
  const int bb = blockIdx.x, t = threadIdx.x;
  const float* Hn = ws + OFF_HN + (size_t)bb * CO * NN;
  if (t < 128) xmean[t] = ws[OFF_XMSUM + (size_t)bb * CO + t] * (1.f / 16384.f) + ws[OFF_BLIN1 + t];
  __syncthreads();
  if (t < 128) {
    float s = bsim[t];
    for (int c = 0; c < 128; ++c) s = fmaf(Wsim[t * 128 + c], xmean[c], s);
    q[t] = s;
  }
  __syncthreads();
  if (t < 128) {
    float s = 0.f;
    for (int o = 0; o < 128; ++o) s = fmaf(Wsim[o * 128 + t], q[o], s);
    u[t] = s;
  }
  float pc = 0.f, pl = 0.f;
  if (t < 128) { pc = q[t] * bsim[t]; pl = q[t] * q[t]; }
  red[t] = pc; __syncthreads();
  for (int s = 128; s > 0; s >>= 1) { if (t < s) red[t] += red[t + s]; __syncthreads(); }
  if (t == 0) cq_sh = red[0];
  __syncthreads();
  red[t] = pl; __syncthreads();
  for (int s = 128; s > 0; s >>= 1) { if (t < s) red[t] += red[t + s]; __syncthreads(); }
  if (t == 0) l0_sh = red[0];
  __syncthreads();
  const float cq = cq_sh;
  for (int n = t; n < 1024; n += 256) {
    float s = cq;
    for (int c = 0; c < 128; ++c) s = fmaf(u[c], Hn[(size_t)c * NN + n], s);
    sim[n + 1] = 1.f / (1.f + expf(-s));
  }
  if (t == 0) sim[0] = 1.f / (1.f + expf(-l0_sh));
  __syncthreads();
  // softmax over 1025 sigmoid values
  float m = -1e30f;
  for (int n = t; n < 1025; n += 256) m = fmaxf(m, sim[n]);
  red[t] = m; __syncthreads();
  for (int s = 128; s > 0; s >>= 1) { if (t < s) red[t] = fmaxf(red[t], red[t + s]); __syncthreads(); }
  if (t == 0) msh = red[0];
  __syncthreads();
  m = msh;
  float pssum = 0.f;
  for (int n = t; n < 1025; n += 256) { float e = expf(sim[n] - m); sim[n] = e; pssum += e; }
  red[t] = pssum; __syncthreads();
  for (int s = 128; s > 0; s >>= 1) { if (t < s) red[t] += red[t + s]; __syncthreads(); }
  if (t == 0) ssh = red[0];
  __syncthreads();
  const float inv = 1.f / ssh;
  // X_aggre[c] = (sim[0]*xmean[c] + sum_n sim[n+1]*Hn[c][n]) * inv
  {
    const int c = t >> 1, hf = t & 1;
    const float* hr = Hn + (size_t)c * NN + hf * 512;
    const float* sr = sim + 1 + hf * 512;
    float pa = 0.f;
    for (int n = 0; n < 512; ++n) pa = fmaf(sr[n], hr[n], pa);
    red[t] = pa;
  }
  __syncthreads();
  if (t < 128) xa[t] = (red[2 * t] + red[2 * t + 1] + sim[0] * xmean[t]) * inv;
  __syncthreads();
  if (t < 128) {
    float s = bscore[t];
    for (int c = 0; c < 128; ++c) s = fmaf(Wscore[t * 128 + c], xa[c], s);
    float sc = 1.f / (1.f + expf(-s));
    ws[OFF_GA + (size_t)bb * CO + t] = sc * xa[t];
    ws[OFF_GB + (size_t)bb * CO + t] = 1.f - sc;
  }
}

// ---------------------------------------------------------------------------
// H_out = prelu(Wf1 @ prelu(Hn,a2) + WfH @ H_in + bfH, fa)  (16,128,1024)
// grid (8,16), block 256.
__global__ __launch_bounds__(256) void k_hout(
    const float* __restrict__ Hin, const float* __restrict__ act2_a,
    const float* __restrict__ final_a, float* ws, float* __restrict__ dout)
{
  __shared__ __align__(16) float smem[2048];
  float* wt = smem;
  float* xb = smem + 1024;
  const float* WT = ws + OFF_WCHT;
  const float* bias = ws + OFF_BFH;
  const float* Hn = ws + OFF_HN;
  const int bb = blockIdx.y;
  const int col0 = blockIdx.x * 128;
  const int tid = threadIdx.x;
  const int ty = tid >> 4, tx = tid & 15;
  const int kk = tid >> 5, j4 = tid & 31;
  const float a2 = act2_a[0], fa = final_a[0];
  float acc[8][8];
#pragma unroll
  for (int i = 0; i < 8; ++i)
#pragma unroll
    for (int j = 0; j < 8; ++j) acc[i][j] = 0.f;
  for (int k0 = 0; k0 < KT; k0 += 8) {
    ((float4*)wt)[tid] = ((const float4*)(WT + (size_t)(k0 + kk) * CO))[j4];
    const int krow = k0 + kk;
    float4 v;
    if (krow < CO) {
      v = ((const float4*)(Hn + ((size_t)(bb * CO + krow)) * NN + col0))[j4];
      v.x = preluf(v.x, a2); v.y = preluf(v.y, a2);
      v.z = preluf(v.z, a2); v.w = preluf(v.w, a2);
    } else {
      v = ((const float4*)(Hin + ((size_t)(bb * CI + (krow - CO))) * NN + col0))[j4];
    }
    ((float4*)xb)[tid] = v;
    __syncthreads();
#pragma unroll
    for (int k = 0; k < 8; ++k) {
      const float* wrow = wt + k * 128 + ty * 8;
      const float* xrow = xb + k * 128 + tx * 8;
      GEMM_FMA_8x8(wrow, xrow);
    }
    __syncthreads();
  }
  float* Hout = dout + (size_t)BB * CO * HW;
#pragma unroll
  for (int i = 0; i < 8; ++i) {
    const int o = ty * 8 + i;
    const float bi = bias[o];
    float r[8];
#pragma unroll
    for (int j = 0; j < 8; ++j) r[j] = preluf(acc[i][j] + bi, fa);
    float* dst = Hout + ((size_t)(bb * CO + o)) * NN + col0 + tx * 8;
    *(float4*)dst       = make_float4(r[0], r[1], r[2], r[3]);
    *(float4*)(dst + 4) = make_float4(r[4], r[5], r[6], r[7]);
  }
}

// ---------------------------------------------------------------------------
// Per (b, y-row): depthwise 3x3 on X + gate + prelu -> Xg in LDS, then
// X_out = prelu(Wf1 @ Xg + WfX @ X_in + bfX, fa).  grid (128,16), block 256.
__global__ __launch_bounds__(256) void k_xout(
    const float* __restrict__ Xin, const float* __restrict__ Wdw,
    const float* __restrict__ bdw, const float* __restrict__ act_a,
    const float* __restrict__ final_a, float* ws, float* __restrict__ dout)
{
  __shared__ __align__(16) float xg[128 * 128];   // 64 KB
  __shared__ __align__(16) float smem[2048];
  __shared__ float wdw[128 * 9];
  __shared__ float gav[128], gbv[128];
  const int bb = blockIdx.y, y = blockIdx.x, tid = threadIdx.x;
  const float* Xw = ws + OFF_X;
  const float aa = act_a[0], fa = final_a[0];
  for (int i = tid; i < 128 * 9; i += 256) wdw[i] = Wdw[i];
  if (tid < 128) {
    gav[tid] = ws[OFF_GA + (size_t)bb * CO + tid];
    gbv[tid] = ws[OFF_GB + (size_t)bb * CO + tid];
  }
  __syncthreads();
  // stage 1: conv + gate + prelu
  {
    const int px = tid & 127, half = tid >> 7;
    for (int c = half; c < CO; c += 2) {
      const float* base = Xw + ((size_t)(bb * CO + c)) * HW + y * IMG_W;
      const float* wc = wdw + c * 9;
      float v = bdw[c];
#pragma unroll
      for (int dy = -1; dy <= 1; ++dy) {
        const int yy = y + dy;
        if (yy < 0 || yy >= IMG_H) continue;
        const float* row = base + dy * IMG_W;
#pragma unroll
        for (int dx = -1; dx <= 1; ++dx) {
          const int xx = px + dx;
          if (xx < 0 || xx >= IMG_W) continue;
          v = fmaf(row[xx], wc[(dy + 1) * 3 + (dx + 1)], v);
        }
      }
      float g = gav[c] + gbv[c] * v;
      xg[c * 128 + px] = preluf(g, aa);
    }
  }
  __syncthreads();
  // stage 2: GEMM K=328 (k<128 from xg LDS, k>=128 from X_in)
  float* wt = smem;
  float* xb = smem + 1024;
  const float* WT = ws + OFF_WCXT;
  const float* bias = ws + OFF_BFX;
  const int ty = tid >> 4, tx = tid & 15;
  const int kk = tid >> 5, j4 = tid & 31;
  float acc[8][8];
#pragma unroll
  for (int i = 0; i < 8; ++i)
#pragma unroll
    for (int j = 0; j < 8; ++j) acc[i][j] = 0.f;
  for (int k0 = 0; k0 < KT; k0 += 8) {
    ((float4*)wt)[tid] = ((const float4*)(WT + (size_t)(k0 + kk) * CO))[j4];
    const bool fromX = (k0 >= CO);
    if (fromX) {
      ((float4*)xb)[tid] =
          ((const float4*)(Xin + ((size_t)(bb * CI + (k0 + kk - CO))) * HW + y * IMG_W))[j4];
    }
    __syncthreads();
    const float* bbase = fromX ? xb : (xg + k0 * 128);
#pragma unroll
    for (int k = 0; k < 8; ++k) {
      const float* wrow = wt + k * 128 + ty * 8;
      const float* xrow = bbase + k * 128 + tx * 8;
      GEMM_FMA_8x8(wrow, xrow);
    }
    __syncthreads();
  }
#pragma unroll
  for (int i = 0; i < 8; ++i) {
    const int o = ty * 8 + i;
    const float bi = bias[o];
    float r[8];
#pragma unroll
    for (int j = 0; j < 8; ++j) r[j] = preluf(acc[i][j] + bi, fa);
    float* dst = dout + ((size_t)(bb * CO + o)) * HW + y * IMG_W + tx * 8;
    *(float4*)dst       = make_float4(r[0], r[1], r[2], r[3]);
    *(float4*)(dst + 4) = make_float4(r[4], r[5], r[6], r[7]);
  }
}

// ---------------------------------------------------------------------------
extern "C" void kernel_launch(void* const* d_in, const int* in_sizes, int n_in,
                              void* d_out, int out_size, void* d_ws, size_t ws_size,
                              hipStream_t stream)
{
  const float* Xin   = (const float*)d_in[0];
  const float* Hin   = (const float*)d_in[1];
  const float* bn1g  = (const float*)d_in[2];
  const float* bn1b  = (const float*)d_in[3];
  const float* bn1m  = (const float*)d_in[4];
  const float* bn1v  = (const float*)d_in[5];
  const float* bn2g  = (const float*)d_in[6];
  const float* bn2b  = (const float*)d_in[7];
  const float* bn2m  = (const float*)d_in[8];
  const float* bn2v  = (const float*)d_in[9];
  const float* Wlin  = (const float*)d_in[10];
  const float* blin  = (const float*)d_in[11];
  const float* Wsim  = (const float*)d_in[12];
  const float* bsim  = (const float*)d_in[13];
  const float* Wscr  = (const float*)d_in[14];
  const float* bscr  = (const float*)d_in[15];
  const float* Wdw   = (const float*)d_in[16];
  const float* bdw   = (const float*)d_in[17];
  const float* Wfin  = (const float*)d_in[18];
  const float* bfin  = (const float*)d_in[19];
  const float* acta  = (const float*)d_in[20];
  const float* act2a = (const float*)d_in[21];
  const float* fina  = (const float*)d_in[22];
  float* ws  = (float*)d_ws;
  float* out = (float*)d_out;

  k_prep<<<dim3(128), dim3(256), 0, stream>>>(bn1g, bn1b, bn1m, bn1v,
                                              bn2g, bn2b, bn2m, bn2v,
                                              Wlin, blin, Wfin, bfin, ws);
  k_hn<<<dim3(8, 16), dim3(256), 0, stream>>>(Hin, ws);
  k_x<<<dim3(128, 16), dim3(256), 0, stream>>>(Xin, ws);
  k_small<<<dim3(16), dim3(256), 0, stream>>>(Wsim, bsim, Wscr, bscr, ws);
  k_hout<<<dim3(8, 16), dim3(256), 0, stream>>>(Hin, act2a, fina, ws, out);
  k_xout<<<dim3(128, 16), dim3(256), 0, stream>>>(Xin, Wdw, bdw, acta, fina, ws, out);
}

// Round 8
// 1137.340 us; speedup vs baseline: 1.1426x; 1.1426x over previous
//
#include <hip/hip_runtime.h>

constexpr int BB = 16;
constexpr int CI = 200;
constexpr int CO = 128;
constexpr int IMG_H = 128;
constexpr int IMG_W = 128;
constexpr int HW = IMG_H * IMG_W;    // 16384
constexpr int NN = 1024;
constexpr int KT = CO + CI;          // 328
constexpr int KP = 224;              // padded K for MFMA path (7 x 32)

// ---------------- workspace layout (float units) ----------------
constexpr size_t F_XBF    = 0;                       // bf16 X [16][128][16384] = 33.5M ushort = 16.7M floats
constexpr size_t F_HN     = 16777216;                // fp32 Hn [16][128][1024]
constexpr size_t F_WLIN1T = F_HN + 2097152;          // [200][128]
constexpr size_t F_WLIN2T = F_WLIN1T + 25600;
constexpr size_t F_BLIN1  = F_WLIN2T + 25600;        // 128
constexpr size_t F_BLIN2  = F_BLIN1 + 128;
constexpr size_t F_WCXT   = F_BLIN2 + 128;           // [328][128]
constexpr size_t F_WCHT   = F_WCXT + 41984;
constexpr size_t F_BFX    = F_WCHT + 41984;
constexpr size_t F_BFH    = F_BFX + 128;
constexpr size_t F_XMSUM  = F_BFH + 128;             // [16][128]
constexpr size_t F_GA     = F_XMSUM + 2048;
constexpr size_t F_GB     = F_GA + 2048;
constexpr size_t F_WB1    = F_GB + 2048;             // bf16 W [128][224] = 28672 ushort
constexpr size_t F_END    = F_WB1 + 14336;           // ~76.1 MB total — fits proven ws

typedef __attribute__((ext_vector_type(8))) short short8v;  // 8 bf16 (4 VGPR)
typedef __attribute__((ext_vector_type(4))) float f32x4;

__device__ __forceinline__ float preluf(float v, float a) { return v >= 0.f ? v : a * v; }
__device__ __forceinline__ ushort f2bf(float f) {
  union { float f; unsigned u; } x; x.f = f;
  unsigned r = (x.u + 0x7FFFu + ((x.u >> 16) & 1u)) >> 16;
  return (ushort)r;
}
__device__ __forceinline__ float bf2f(ushort u) {
  union { unsigned u; float f; } x; x.u = ((unsigned)u) << 16;
  return x.f;
}

#define GEMM_FMA_8x8(wrow, xrow)                                        \
  {                                                                     \
    float4 a0 = *(const float4*)(wrow);                                 \
    float4 a1 = *(const float4*)((wrow) + 4);                           \
    float4 b0 = *(const float4*)(xrow);                                 \
    float4 b1 = *(const float4*)((xrow) + 4);                           \
    float av[8] = {a0.x, a0.y, a0.z, a0.w, a1.x, a1.y, a1.z, a1.w};     \
    float bv[8] = {b0.x, b0.y, b0.z, b0.w, b1.x, b1.y, b1.z, b1.w};     \
    _Pragma("unroll")                                                   \
    for (int ii = 0; ii < 8; ++ii)                                      \
      _Pragma("unroll")                                                 \
      for (int jj = 0; jj < 8; ++jj)                                    \
        acc[ii][jj] = fmaf(av[ii], bv[jj], acc[ii][jj]);                \
  }

// B-operand in bf16 (uint4 = 8 bf16)
#define GEMM_FMA_8x8_BF(wrow, xrowu)                                    \
  {                                                                     \
    float4 a0 = *(const float4*)(wrow);                                 \
    float4 a1 = *(const float4*)((wrow) + 4);                           \
    uint4 bu = *(const uint4*)(xrowu);                                  \
    float av[8] = {a0.x, a0.y, a0.z, a0.w, a1.x, a1.y, a1.z, a1.w};     \
    float bv[8] = {bf2f((ushort)(bu.x & 0xffff)), bf2f((ushort)(bu.x >> 16)), \
                   bf2f((ushort)(bu.y & 0xffff)), bf2f((ushort)(bu.y >> 16)), \
                   bf2f((ushort)(bu.z & 0xffff)), bf2f((ushort)(bu.z >> 16)), \
                   bf2f((ushort)(bu.w & 0xffff)), bf2f((ushort)(bu.w >> 16))}; \
    _Pragma("unroll")                                                   \
    for (int ii = 0; ii < 8; ++ii)                                      \
      _Pragma("unroll")                                                 \
      for (int jj = 0; jj < 8; ++jj)                                    \
        acc[ii][jj] = fmaf(av[ii], bv[jj], acc[ii][jj]);                \
  }

// ---------------------------------------------------------------------------
// Fold BN into weights; fp32 transposed tables + bf16 MFMA A-table.
// grid 128 (one o), block 256.
__global__ __launch_bounds__(256) void k_prep(
    const float* __restrict__ bn1g, const float* __restrict__ bn1b,
    const float* __restrict__ bn1m, const float* __restrict__ bn1v,
    const float* __restrict__ bn2g, const float* __restrict__ bn2b,
    const float* __restrict__ bn2m, const float* __restrict__ bn2v,
    const float* __restrict__ Wlin, const float* __restrict__ blin,
    const float* __restrict__ Wfin, const float* __restrict__ bfin,
    float* __restrict__ wlin1t, float* __restrict__ wlin2t,
    float* __restrict__ blin1, float* __restrict__ blin2,
    float* __restrict__ wcxt, float* __restrict__ wcht,
    float* __restrict__ bfx, float* __restrict__ bfh,
    float* __restrict__ xmsum, ushort* __restrict__ wb1)
{
  __shared__ float a1[CI], d1[CI], a2[CI], d2[CI];
  __shared__ float red[256];
  const int o = blockIdx.x;
  const int t = threadIdx.x;
  if (t < CI) {
    float s1 = bn1g[t] * rsqrtf(bn1v[t] + 1e-5f);
    a1[t] = s1; d1[t] = bn1b[t] - bn1m[t] * s1;
    float s2 = bn2g[t] * rsqrtf(bn2v[t] + 1e-5f);
    a2[t] = s2; d2[t] = bn2b[t] - bn2m[t] * s2;
  }
  __syncthreads();
  if (t < CI) {
    float w = Wlin[o * CI + t];
    wlin1t[(size_t)t * CO + o] = w * a1[t];
    wlin2t[(size_t)t * CO + o] = w * a2[t];
  }
  if (t < KP) {
    float v = (t < CI) ? Wlin[o * CI + t] * a1[t] : 0.f;
    wb1[o * KP + t] = f2bf(v);
  }
  for (int k = t; k < KT; k += 256) {
    float w = Wfin[o * KT + k];
    float wx = w, wh = w;
    if (k >= CO) { wx = w * a1[k - CO]; wh = w * a2[k - CO]; }
    wcxt[(size_t)k * CO + o] = wx;
    wcht[(size_t)k * CO + o] = wh;
  }
  if (t < BB) xmsum[(size_t)t * CO + o] = 0.f;

  float p1 = 0.f, p2 = 0.f, p3 = 0.f, p4 = 0.f;
  if (t < CI) {
    float wl = Wlin[o * CI + t];
    float wf = Wfin[o * KT + CO + t];
    p1 = wl * d1[t]; p2 = wl * d2[t];
    p3 = wf * d1[t]; p4 = wf * d2[t];
  }
  __syncthreads();
  red[t] = p1; __syncthreads();
  for (int s = 128; s > 0; s >>= 1) { if (t < s) red[t] += red[t + s]; __syncthreads(); }
  if (t == 0) blin1[o] = blin[o] + red[0];
  __syncthreads();
  red[t] = p2; __syncthreads();
  for (int s = 128; s > 0; s >>= 1) { if (t < s) red[t] += red[t + s]; __syncthreads(); }
  if (t == 0) blin2[o] = blin[o] + red[0];
  __syncthreads();
  red[t] = p3; __syncthreads();
  for (int s = 128; s > 0; s >>= 1) { if (t < s) red[t] += red[t + s]; __syncthreads(); }
  if (t == 0) bfx[o] = bfin[o] + red[0];
  __syncthreads();
  red[t] = p4; __syncthreads();
  for (int s = 128; s > 0; s >>= 1) { if (t < s) red[t] += red[t + s]; __syncthreads(); }
  if (t == 0) bfh[o] = bfin[o] + red[0];
}

// ---------------------------------------------------------------------------
// MFMA GEMM: X = Wb(bf16) @ BN1(X_in)(bf16) + bias -> bf16 X + fused mean-sums.
// B-tile is transposed IN-KERNEL from X_in (f32, n-contiguous) into a
// k-contiguous XOR-swizzled LDS tile; no XT buffer, no k_tx kernel.
// grid (128 nb, 16 b), block 256 = 4 waves (wave -> 64o x 64n quadrant).
__global__ __launch_bounds__(256) void k_x_mfma(
    const float* __restrict__ Xin, const ushort* __restrict__ Wb,
    const float* __restrict__ bias, ushort* __restrict__ XBF,
    float* __restrict__ xmsum)
{
  __shared__ __align__(16) ushort lds[8192];  // A [0,4096) B [4096,8192) ushort idx
  const int b = blockIdx.y;
  const int n0 = blockIdx.x * 128;
  const int tid = threadIdx.x;
  const int l = tid & 63, w = tid >> 6;
  const int wr = w >> 1, wc = w & 1;
  const int g = l >> 4, r15 = l & 15;

  // --- A staging: 2 uint4 chunks/thread (tile [128 o][32 k] bf16, swizzled)
  int aoff[2];
  size_t agl[2];
#pragma unroll
  for (int r = 0; r < 2; ++r) {
    int id = r * 256 + tid;
    int row = id >> 2, cs = id & 3;
    int cd = cs ^ ((row >> 1) & 3);
    aoff[r] = row * 32 + cs * 8;
    agl[r] = (size_t)row * KP + cd * 8;
  }
  // --- B staging: thread owns column n (=tid&127), 16 contiguous k (half=tid>>7)
  const int nB = tid & 127, khB = tid >> 7;
  const int sB = (nB >> 1) & 3;
  const int bw0 = 4096 + nB * 32 + (((2 * khB)     ^ sB) * 8);
  const int bw1 = 4096 + nB * 32 + (((2 * khB + 1) ^ sB) * 8);
  const float* bsrc = Xin + (size_t)b * CI * HW + n0 + nB;

  // --- fragment read offsets (swizzle-consistent)
  int aidx[4], bidx[4];
#pragma unroll
  for (int mi = 0; mi < 4; ++mi) {
    int o = wr * 64 + mi * 16 + r15;
    aidx[mi] = o * 32 + ((g ^ ((o >> 1) & 3)) * 8);
  }
#pragma unroll
  for (int ni = 0; ni < 4; ++ni) {
    int n = wc * 64 + ni * 16 + r15;
    bidx[ni] = 4096 + n * 32 + ((g ^ ((n >> 1) & 3)) * 8);
  }

  f32x4 acc[4][4];
#pragma unroll
  for (int mi = 0; mi < 4; ++mi)
#pragma unroll
    for (int ni = 0; ni < 4; ++ni) acc[mi][ni] = (f32x4)(0.f);

  uint4 areg0 = *(const uint4*)(Wb + agl[0]);
  uint4 areg1 = *(const uint4*)(Wb + agl[1]);
  float bregs[16];
#pragma unroll
  for (int j = 0; j < 16; ++j) {
    const int k = khB * 16 + j;  // step 0: always < CI
    bregs[j] = bsrc[(size_t)k * HW];
  }

  for (int ks = 0; ks < 7; ++ks) {
    *(uint4*)(lds + aoff[0]) = areg0;
    *(uint4*)(lds + aoff[1]) = areg1;
    unsigned pk[8];
#pragma unroll
    for (int q = 0; q < 8; ++q)
      pk[q] = (unsigned)f2bf(bregs[2 * q]) | ((unsigned)f2bf(bregs[2 * q + 1]) << 16);
    *(uint4*)(lds + bw0) = make_uint4(pk[0], pk[1], pk[2], pk[3]);
    *(uint4*)(lds + bw1) = make_uint4(pk[4], pk[5], pk[6], pk[7]);
    __syncthreads();
    if (ks < 6) {  // issue next-step loads; MFMA phase hides latency (T14)
      const size_t ko = (size_t)(ks + 1) * 32;
      areg0 = *(const uint4*)(Wb + agl[0] + ko);
      areg1 = *(const uint4*)(Wb + agl[1] + ko);
#pragma unroll
      for (int j = 0; j < 16; ++j) {
        const int k = (ks + 1) * 32 + khB * 16 + j;  // wave-uniform guard
        bregs[j] = (k < CI) ? bsrc[(size_t)k * HW] : 0.f;
      }
    }
    short8v av[4], bv[4];
#pragma unroll
    for (int mi = 0; mi < 4; ++mi) av[mi] = *(const short8v*)(lds + aidx[mi]);
#pragma unroll
    for (int ni = 0; ni < 4; ++ni) bv[ni] = *(const short8v*)(lds + bidx[ni]);
#pragma unroll
    for (int mi = 0; mi < 4; ++mi)
#pragma unroll
      for (int ni = 0; ni < 4; ++ni)
        acc[mi][ni] = __builtin_amdgcn_mfma_f32_16x16x32_bf16(av[mi], bv[ni], acc[mi][ni], 0, 0, 0);
    __syncthreads();
  }

  // epilogue: bias + bf16 store (C/D: col=lane&15, row=(lane>>4)*4+e)
#pragma unroll
  for (int mi = 0; mi < 4; ++mi)
#pragma unroll
    for (int e = 0; e < 4; ++e) {
      const int o = wr * 64 + mi * 16 + g * 4 + e;
      const float bi = bias[o];
      const size_t rowbase = ((size_t)(b * CO + o)) * HW + n0;
#pragma unroll
      for (int ni = 0; ni < 4; ++ni) {
        const int n = wc * 64 + ni * 16 + r15;
        XBF[rowbase + n] = f2bf(acc[mi][ni][e] + bi);
      }
    }
  // fused mean partial sums (pre-bias)
  float* red = (float*)lds;  // [128][32] = 16KB
#pragma unroll
  for (int mi = 0; mi < 4; ++mi)
#pragma unroll
    for (int e = 0; e < 4; ++e) {
      const int o = wr * 64 + mi * 16 + g * 4 + e;
      float s = acc[mi][0][e] + acc[mi][1][e] + acc[mi][2][e] + acc[mi][3][e];
      red[o * 32 + wc * 16 + r15] = s;
    }
  __syncthreads();
  if (tid < 128) {
    float s = 0.f;
#pragma unroll
    for (int j = 0; j < 32; ++j) s += red[tid * 32 + j];
    atomicAdd(xmsum + (size_t)b * CO + tid, s);
  }
}

// ---------------------------------------------------------------------------
// Hn = Wlin2 @ H_in + blin2. grid (8,16), block 256.
__global__ __launch_bounds__(256) void k_hn(const float* __restrict__ Hin,
                                            const float* __restrict__ WT,
                                            const float* __restrict__ bias,
                                            float* __restrict__ Hn)
{
  __shared__ __align__(16) float smem[2048];
  float* wt = smem;
  float* xb = smem + 1024;
  const int bb = blockIdx.y;
  const int col0 = blockIdx.x * 128;
  const int tid = threadIdx.x;
  const int ty = tid >> 4, tx = tid & 15;
  const int kk = tid >> 5, j4 = tid & 31;
  float acc[8][8];
#pragma unroll
  for (int i = 0; i < 8; ++i)
#pragma unroll
    for (int j = 0; j < 8; ++j) acc[i][j] = 0.f;
  const float* Bsrc = Hin + (size_t)bb * CI * NN + col0;
  for (int k0 = 0; k0 < CI; k0 += 8) {
    ((float4*)wt)[tid] = ((const float4*)(WT + (size_t)(k0 + kk) * CO))[j4];
    ((float4*)xb)[tid] = ((const float4*)(Bsrc + (size_t)(k0 + kk) * NN))[j4];
    __syncthreads();
#pragma unroll
    for (int k = 0; k < 8; ++k) {
      const float* wrow = wt + k * 128 + ty * 8;
      const float* xrow = xb + k * 128 + tx * 8;
      GEMM_FMA_8x8(wrow, xrow);
    }
    __syncthreads();
  }
#pragma unroll
  for (int i = 0; i < 8; ++i) {
    const int o = ty * 8 + i;
    const float bi = bias[o];
    float* dst = Hn + ((size_t)(bb * CO + o)) * NN + col0 + tx * 8;
    *(float4*)dst       = make_float4(acc[i][0] + bi, acc[i][1] + bi, acc[i][2] + bi, acc[i][3] + bi);
    *(float4*)(dst + 4) = make_float4(acc[i][4] + bi, acc[i][5] + bi, acc[i][6] + bi, acc[i][7] + bi);
  }
}

// ---------------------------------------------------------------------------
// Per-batch attention/gate scalars. grid 16, block 256.
__global__ __launch_bounds__(256) void k_small(
    const float* __restrict__ Wsim, const float* __restrict__ bsim,
    const float* __restrict__ Wscore, const float* __restrict__ bscore,
    const float* __restrict__ HnG, const float* __restrict__ xmsum,
    const float* __restrict__ blin1, float* __restrict__ ga,
    float* __restrict__ gb)
{
  __shared__ float xmean[128], q[128], u[128], xa[128];
  __shared__ float sim[1025];
  __shared__ float red[256];
  __shared__ float cq_sh, l0_sh, msh, ssh;
  const int bb = blockIdx.x, t = threadIdx.x;
  const float* Hn = HnG + (size_t)bb * CO * NN;
  if (t < 128) xmean[t] = xmsum[(size_t)bb * CO + t] * (1.f / 16384.f) + blin1[t];
  __syncthreads();
  if (t < 128) {
    float s = bsim[t];
    for (int c = 0; c < 128; ++c) s = fmaf(Wsim[t * 128 + c], xmean[c], s);
    q[t] = s;
  }
  __syncthreads();
  if (t < 128) {
    float s = 0.f;
    for (int o = 0; o < 128; ++o) s = fmaf(Wsim[o * 128 + t], q[o], s);
    u[t] = s;
  }
  float pc = 0.f, pl = 0.f;
  if (t < 128) { pc = q[t] * bsim[t]; pl = q[t] * q[t]; }
  red[t] = pc; __syncthreads();
  for (int s = 128; s > 0; s >>= 1) { if (t < s) red[t] += red[t + s]; __syncthreads(); }
  if (t == 0) cq_sh = red[0];
  __syncthreads();
  red[t] = pl; __syncthreads();
  for (int s = 128; s > 0; s >>= 1) { if (t < s) red[t] += red[t + s]; __syncthreads(); }
  if (t == 0) l0_sh = red[0];
  __syncthreads();
  const float cq = cq_sh;
  for (int n = t; n < 1024; n += 256) {
    float s = cq;
    for (int c = 0; c < 128; ++c) s = fmaf(u[c], Hn[(size_t)c * NN + n], s);
    sim[n + 1] = 1.f / (1.f + expf(-s));
  }
  if (t == 0) sim[0] = 1.f / (1.f + expf(-l0_sh));
  __syncthreads();
  float m = -1e30f;
  for (int n = t; n < 1025; n += 256) m = fmaxf(m, sim[n]);
  red[t] = m; __syncthreads();
  for (int s = 128; s > 0; s >>= 1) { if (t < s) red[t] = fmaxf(red[t], red[t + s]); __syncthreads(); }
  if (t == 0) msh = red[0];
  __syncthreads();
  m = msh;
  float pssum = 0.f;
  for (int n = t; n < 1025; n += 256) { float e = expf(sim[n] - m); sim[n] = e; pssum += e; }
  red[t] = pssum; __syncthreads();
  for (int s = 128; s > 0; s >>= 1) { if (t < s) red[t] += red[t + s]; __syncthreads(); }
  if (t == 0) ssh = red[0];
  __syncthreads();
  const float inv = 1.f / ssh;
  {
    const int c = t >> 1, hf = t & 1;
    const float* hr = Hn + (size_t)c * NN + hf * 512;
    const float* sr = sim + 1 + hf * 512;
    float pa = 0.f;
    for (int n = 0; n < 512; ++n) pa = fmaf(sr[n], hr[n], pa);
    red[t] = pa;
  }
  __syncthreads();
  if (t < 128) xa[t] = (red[2 * t] + red[2 * t + 1] + sim[0] * xmean[t]) * inv;
  __syncthreads();
  if (t < 128) {
    float s = bscore[t];
    for (int c = 0; c < 128; ++c) s = fmaf(Wscore[t * 128 + c], xa[c], s);
    float sc = 1.f / (1.f + expf(-s));
    ga[(size_t)bb * CO + t] = sc * xa[t];
    gb[(size_t)bb * CO + t] = 1.f - sc;
  }
}

// ---------------------------------------------------------------------------
// H_out. grid (8,16), block 256.
__global__ __launch_bounds__(256) void k_hout(
    const float* __restrict__ Hin, const float* __restrict__ act2_a,
    const float* __restrict__ final_a, const float* __restrict__ WT,
    const float* __restrict__ bias, const float* __restrict__ HnG,
    float* __restrict__ dout)
{
  __shared__ __align__(16) float smem[2048];
  float* wt = smem;
  float* xb = smem + 1024;
  const int bb = blockIdx.y;
  const int col0 = blockIdx.x * 128;
  const int tid = threadIdx.x;
  const int ty = tid >> 4, tx = tid & 15;
  const int kk = tid >> 5, j4 = tid & 31;
  const float a2 = act2_a[0], fa = final_a[0];
  float acc[8][8];
#pragma unroll
  for (int i = 0; i < 8; ++i)
#pragma unroll
    for (int j = 0; j < 8; ++j) acc[i][j] = 0.f;
  for (int k0 = 0; k0 < KT; k0 += 8) {
    ((float4*)wt)[tid] = ((const float4*)(WT + (size_t)(k0 + kk) * CO))[j4];
    const int krow = k0 + kk;
    float4 v;
    if (krow < CO) {
      v = ((const float4*)(HnG + ((size_t)(bb * CO + krow)) * NN + col0))[j4];
      v.x = preluf(v.x, a2); v.y = preluf(v.y, a2);
      v.z = preluf(v.z, a2); v.w = preluf(v.w, a2);
    } else {
      v = ((const float4*)(Hin + ((size_t)(bb * CI + (krow - CO))) * NN + col0))[j4];
    }
    ((float4*)xb)[tid] = v;
    __syncthreads();
#pragma unroll
    for (int k = 0; k < 8; ++k) {
      const float* wrow = wt + k * 128 + ty * 8;
      const float* xrow = xb + k * 128 + tx * 8;
      GEMM_FMA_8x8(wrow, xrow);
    }
    __syncthreads();
  }
  float* Hout = dout + (size_t)BB * CO * HW;
#pragma unroll
  for (int i = 0; i < 8; ++i) {
    const int o = ty * 8 + i;
    const float bi = bias[o];
    float r[8];
#pragma unroll
    for (int j = 0; j < 8; ++j) r[j] = preluf(acc[i][j] + bi, fa);
    float* dst = Hout + ((size_t)(bb * CO + o)) * NN + col0 + tx * 8;
    *(float4*)dst       = make_float4(r[0], r[1], r[2], r[3]);
    *(float4*)(dst + 4) = make_float4(r[4], r[5], r[6], r[7]);
  }
}

// ---------------------------------------------------------------------------
// Depthwise 3x3 (bf16 X) + gate + prelu -> xg(bf16 LDS), then K=328 GEMM with
// register-prefetched staging. grid (128,16), block 256. LDS ~43.6KB (3 blk/CU).
__global__ __launch_bounds__(256) void k_xout(
    const float* __restrict__ Xin, const ushort* __restrict__ XBF,
    const float* __restrict__ Wdw, const float* __restrict__ bdw,
    const float* __restrict__ act_a, const float* __restrict__ final_a,
    const float* __restrict__ wcxt, const float* __restrict__ bfx,
    const float* __restrict__ ga, const float* __restrict__ gb,
    float* __restrict__ dout)
{
  __shared__ __align__(16) ushort xg[128 * 128];  // 32KB bf16
  __shared__ __align__(16) float wt[1024];        // 4KB
  __shared__ __align__(16) ushort xb[1024];       // 2KB
  __shared__ float wdw[1152];
  __shared__ float gav[128], gbv[128];
  const int bb = blockIdx.y, y = blockIdx.x, tid = threadIdx.x;
  const float aa = act_a[0], fa = final_a[0];
  for (int i = tid; i < 1152; i += 256) wdw[i] = Wdw[i];
  if (tid < 128) {
    gav[tid] = ga[(size_t)bb * CO + tid];
    gbv[tid] = gb[(size_t)bb * CO + tid];
  }
  __syncthreads();
  // stage 1: depthwise conv + gate + prelu
  {
    const int px = tid & 127, half = tid >> 7;
    for (int c = half; c < CO; c += 2) {
      const ushort* base = XBF + ((size_t)(bb * CO + c)) * HW + y * IMG_W;
      const float* wc = wdw + c * 9;
      float v = bdw[c];
#pragma unroll
      for (int dy = -1; dy <= 1; ++dy) {
        const int yy = y + dy;
        if (yy < 0 || yy >= IMG_H) continue;
        const ushort* row = base + dy * IMG_W;
#pragma unroll
        for (int dx = -1; dx <= 1; ++dx) {
          const int xx = px + dx;
          if (xx < 0 || xx >= IMG_W) continue;
          v = fmaf(bf2f(row[xx]), wc[(dy + 1) * 3 + (dx + 1)], v);
        }
      }
      float gv = gav[c] + gbv[c] * v;
      xg[c * 128 + px] = f2bf(preluf(gv, aa));
    }
  }
  __syncthreads();
  // stage 2: GEMM K=328 (k<128 from xg, k>=128 from X_in) with reg prefetch
  const int ty = tid >> 4, tx = tid & 15;
  const int kk8 = tid >> 5, j4 = tid & 31;
  float acc[8][8];
#pragma unroll
  for (int i = 0; i < 8; ++i)
#pragma unroll
    for (int j = 0; j < 8; ++j) acc[i][j] = 0.f;
  float4 wreg = ((const float4*)(wcxt + (size_t)kk8 * CO))[j4];
  float4 xreg = make_float4(0.f, 0.f, 0.f, 0.f);
  for (int k0 = 0; k0 < KT; k0 += 8) {
    ((float4*)wt)[tid] = wreg;
    const bool fromX = (k0 >= CO);
    if (fromX) {
      uint2 p;
      p.x = (unsigned)f2bf(xreg.x) | ((unsigned)f2bf(xreg.y) << 16);
      p.y = (unsigned)f2bf(xreg.z) | ((unsigned)f2bf(xreg.w) << 16);
      ((uint2*)xb)[tid] = p;
    }
    __syncthreads();
    if (k0 + 8 < KT) {  // prefetch next tile; FMA below hides latency
      wreg = ((const float4*)(wcxt + (size_t)(k0 + 8 + kk8) * CO))[j4];
      if (k0 + 8 >= CO)
        xreg = ((const float4*)(Xin + ((size_t)(bb * CI + (k0 + 8 + kk8 - CO))) * HW + y * IMG_W))[j4];
    }
    const ushort* bbase = fromX ? xb : (xg + k0 * 128);
#pragma unroll
    for (int k = 0; k < 8; ++k) {
      const float* wrow = wt + k * 128 + ty * 8;
      const ushort* xrow = bbase + k * 128 + tx * 8;
      GEMM_FMA_8x8_BF(wrow, xrow);
    }
    __syncthreads();
  }
#pragma unroll
  for (int i = 0; i < 8; ++i) {
    const int o = ty * 8 + i;
    const float bi = bfx[o];
    float r[8];
#pragma unroll
    for (int j = 0; j < 8; ++j) r[j] = preluf(acc[i][j] + bi, fa);
    float* dst = dout + ((size_t)(bb * CO + o)) * HW + y * IMG_W + tx * 8;
    *(float4*)dst       = make_float4(r[0], r[1], r[2], r[3]);
    *(float4*)(dst + 4) = make_float4(r[4], r[5], r[6], r[7]);
  }
}

// ---------------------------------------------------------------------------
extern "C" void kernel_launch(void* const* d_in, const int* in_sizes, int n_in,
                              void* d_out, int out_size, void* d_ws, size_t ws_size,
                              hipStream_t stream)
{
  const float* Xin   = (const float*)d_in[0];
  const float* Hin   = (const float*)d_in[1];
  const float* bn1g  = (const float*)d_in[2];
  const float* bn1b  = (const float*)d_in[3];
  const float* bn1m  = (const float*)d_in[4];
  const float* bn1v  = (const float*)d_in[5];
  const float* bn2g  = (const float*)d_in[6];
  const float* bn2b  = (const float*)d_in[7];
  const float* bn2m  = (const float*)d_in[8];
  const float* bn2v  = (const float*)d_in[9];
  const float* Wlin  = (const float*)d_in[10];
  const float* blin  = (const float*)d_in[11];
  const float* Wsim  = (const float*)d_in[12];
  const float* bsim  = (const float*)d_in[13];
  const float* Wscr  = (const float*)d_in[14];
  const float* bscr  = (const float*)d_in[15];
  const float* Wdw   = (const float*)d_in[16];
  const float* bdw   = (const float*)d_in[17];
  const float* Wfin  = (const float*)d_in[18];
  const float* bfin  = (const float*)d_in[19];
  const float* acta  = (const float*)d_in[20];
  const float* act2a = (const float*)d_in[21];
  const float* fina  = (const float*)d_in[22];
  float* wsf = (float*)d_ws;
  float* out = (float*)d_out;

  ushort* XBF   = (ushort*)d_ws;
  float*  HN    = wsf + F_HN;
  float*  WL1T  = wsf + F_WLIN1T;
  float*  WL2T  = wsf + F_WLIN2T;
  float*  BL1   = wsf + F_BLIN1;
  float*  BL2   = wsf + F_BLIN2;
  float*  WCXTp = wsf + F_WCXT;
  float*  WCHTp = wsf + F_WCHT;
  float*  BFXp  = wsf + F_BFX;
  float*  BFHp  = wsf + F_BFH;
  float*  XMS   = wsf + F_XMSUM;
  float*  GAp   = wsf + F_GA;
  float*  GBp   = wsf + F_GB;
  ushort* WB1   = (ushort*)(wsf + F_WB1);

  k_prep<<<dim3(128), dim3(256), 0, stream>>>(
      bn1g, bn1b, bn1m, bn1v, bn2g, bn2b, bn2m, bn2v, Wlin, blin, Wfin, bfin,
      WL1T, WL2T, BL1, BL2, WCXTp, WCHTp, BFXp, BFHp, XMS, WB1);
  k_hn<<<dim3(8, 16), dim3(256), 0, stream>>>(Hin, WL2T, BL2, HN);
  k_x_mfma<<<dim3(128, 16), dim3(256), 0, stream>>>(Xin, WB1, BL1, XBF, XMS);
  k_small<<<dim3(16), dim3(256), 0, stream>>>(Wsim, bsim, Wscr, bscr, HN, XMS, BL1, GAp, GBp);
  k_hout<<<dim3(8, 16), dim3(256), 0, stream>>>(Hin, act2a, fina, WCHTp, BFHp, HN, out);
  k_xout<<<dim3(128, 16), dim3(256), 0, stream>>>(Xin, XBF, Wdw, bdw, acta, fina,
                                                  WCXTp, BFXp, GAp, GBp, out);
}